// Round 15
// baseline (348.810 us; speedup 1.0000x reference)
//
#include <hip/hip_runtime.h>

typedef __bf16 bf16_t;
typedef __bf16 bf16x4 __attribute__((ext_vector_type(4)));
typedef __bf16 bf16x8 __attribute__((ext_vector_type(8)));
typedef float f32x4 __attribute__((ext_vector_type(4)));
typedef float f32x16 __attribute__((ext_vector_type(16)));
typedef unsigned int uint;
typedef uint uint2v __attribute__((ext_vector_type(2)));
typedef uint uint4v __attribute__((ext_vector_type(4)));

#define CSCALE 0.18033688011112042f  // 0.125 * log2(e)

static __device__ __forceinline__ bf16_t f2bf(float f) {
  unsigned u = __builtin_bit_cast(unsigned, f);
  u = (u + 0x7fff + ((u >> 16) & 1)) >> 16;
  unsigned short h = (unsigned short)u;
  return __builtin_bit_cast(bf16_t, h);
}
static __device__ __forceinline__ uint cvt_pk(float a, float b) {
  uint r;
  asm("v_cvt_pk_bf16_f32 %0, %1, %2" : "=v"(r) : "v"(a), "v"(b));
  return r;
}

#define GLD_LDS(g, l) \
  __builtin_amdgcn_global_load_lds((const __attribute__((address_space(1))) void*)(g), \
                                   (__attribute__((address_space(3))) void*)(l), 16, 0, 0)
#define VMCNT(n) asm volatile("s_waitcnt vmcnt(" #n ")" ::: "memory")
#define LGKM0() asm volatile("s_waitcnt lgkmcnt(0)" ::: "memory")
#define BARRIER() do { __builtin_amdgcn_s_barrier(); __builtin_amdgcn_sched_barrier(0); } while (0)

// ---------------- conversion kernels ----------------
__global__ void cvt4_f2b(const float* __restrict__ a, const float* __restrict__ b,
                         const float* __restrict__ c, const float* __restrict__ d,
                         bf16_t* __restrict__ oa, bf16_t* __restrict__ ob,
                         bf16_t* __restrict__ oc, bf16_t* __restrict__ od) {
  int i = blockIdx.x * 256 + threadIdx.x;  // 4 * 262144
  const float* src = a;
  bf16_t* dst = oa;
  int w = i >> 18;
  i &= 262143;
  if (w == 1) { src = b; dst = ob; }
  else if (w == 2) { src = c; dst = oc; }
  else if (w == 3) { src = d; dst = od; }
  const float4 f = reinterpret_cast<const float4*>(src)[i];
  bf16x4 o;
  o[0] = f2bf(f.x); o[1] = f2bf(f.y); o[2] = f2bf(f.z); o[3] = f2bf(f.w);
  reinterpret_cast<bf16x4*>(dst)[i] = o;
}

__global__ void mask_bits_k(const int* __restrict__ m, uint* __restrict__ out) {
  int i = blockIdx.x * 256 + threadIdx.x;  // 131072
  int q = i & 2047, t = i >> 11;
  const int* mrow = m + (size_t)q * 2048 + t * 32;
  uint bits = 0;
#pragma unroll
  for (int j = 0; j < 16; ++j) {
    int r0 = (j & 3) + 8 * (j >> 2);
    bits |= (mrow[r0] ? 1u : 0u) << j;
    bits |= (mrow[r0 + 4] ? 1u : 0u) << (16 + j);
  }
  out[(size_t)t * 2048 + q] = bits;
}

// ---------------- merged QKV GEMM: 128x256 tile, bf16 LDS, reg-staged A (R10) ----------------
__global__ __launch_bounds__(256, 2) void qkv_gemm(
    const float* __restrict__ qA, const float* __restrict__ kA, const float* __restrict__ vA,
    const bf16_t* __restrict__ wq, const bf16_t* __restrict__ wk, const bf16_t* __restrict__ wv,
    const float* __restrict__ bq, const float* __restrict__ bk, const float* __restrict__ bv,
    bf16_t* __restrict__ Qp, bf16_t* __restrict__ Kp, bf16_t* __restrict__ Vt) {
  constexpr int K = 1024;
  __shared__ __align__(16) bf16_t AsB[2][128 * 32];   // 2 x 8 KB
  __shared__ __align__(16) bf16_t BsB[3][256 * 32];   // 3 x 16 KB
  const int z = blockIdx.z;
  const float* A = (z == 0) ? qA : (z == 1) ? kA : vA;
  const bf16_t* W = (z == 0) ? wq : (z == 1) ? wk : wv;
  const float* bias = (z == 0) ? bq : (z == 1) ? bk : bv;

  const int tid = threadIdx.x;
  const int lane = tid & 63;
  const int wv_ = tid >> 6;
  const int wm = (wv_ & 1) * 64, wn = (wv_ >> 1) * 128;
  const int l15 = lane & 15, lhi = lane >> 4;
  const int bm = blockIdx.x, bn = blockIdx.y;

  const int arow0 = tid >> 3;  // 0..31
  const int acol = tid & 7;    // 0..7
  const float* gA = A + (size_t)(bm * 128 + arow0) * K + acol * 4;
  const int brows = tid >> 2;
  const bf16_t* gB = W + (size_t)(bn * 256 + brows) * K + ((tid & 3) ^ (brows & 3)) * 8;

  f32x4 acc[4][8] = {};
  f32x4 rA0[4], rA1[4];

  auto A_LOAD = [&](int t, f32x4* R) {
#pragma unroll
    for (int L = 0; L < 4; ++L)
      R[L] = *reinterpret_cast<const f32x4*>(gA + (size_t)L * 32 * K + t * 32);
  };
  auto A_WRITE = [&](const f32x4* R, int buf) {
#pragma unroll
    for (int L = 0; L < 4; ++L) {
      int row = arow0 + L * 32;
      uint2v u;
      u[0] = cvt_pk(R[L][0], R[L][1]);
      u[1] = cvt_pk(R[L][2], R[L][3]);
      char* p = (char*)&AsB[buf][0] + row * 64 + (((acol >> 1) ^ (row & 3)) * 16) + (acol & 1) * 8;
      *reinterpret_cast<uint2v*>(p) = u;
    }
  };
  auto B_STAGE = [&](int t, int buf) {
#pragma unroll
    for (int c2 = 0; c2 < 4; ++c2)
      GLD_LDS(gB + (size_t)c2 * 64 * K + t * 32, (char*)&BsB[buf][0] + c2 * 4096 + wv_ * 1024);
  };
  auto COMPUTE = [&](int ba, int bb) {
    bf16x8 af[4], bfv[8];
#pragma unroll
    for (int i = 0; i < 4; ++i) {
      int arow = wm + i * 16 + l15;
      af[i] = *reinterpret_cast<const bf16x8*>(
          (const char*)&AsB[ba][0] + arow * 64 + ((lhi ^ (arow & 3)) * 16));
    }
#pragma unroll
    for (int j = 0; j < 8; ++j) {
      int br = wn + j * 16 + l15;
      bfv[j] = *reinterpret_cast<const bf16x8*>(
          (const char*)&BsB[bb][0] + br * 64 + ((lhi ^ (br & 3)) * 16));
    }
#pragma unroll
    for (int i = 0; i < 4; ++i)
#pragma unroll
      for (int j = 0; j < 8; ++j)
        acc[i][j] = __builtin_amdgcn_mfma_f32_16x16x32_bf16(af[i], bfv[j], acc[i][j], 0, 0, 0);
  };

#define QSTEP(T, RL, RW, BAW, BAC, BBC, BBS) \
  A_LOAD((T) + 2, RL); B_STAGE((T) + 2, BBS); \
  COMPUTE(BAC, BBC); \
  VMCNT(8); \
  A_WRITE(RW, BAW); \
  LGKM0(); BARRIER();

  A_LOAD(0, rA0); B_STAGE(0, 0);
  A_LOAD(1, rA1); B_STAGE(1, 1);
  VMCNT(8);
  A_WRITE(rA0, 0);
  LGKM0(); BARRIER();

#pragma unroll 1
  for (int t6 = 0; t6 < 30; t6 += 6) {
    QSTEP(t6 + 0, rA0, rA1, 1, 0, 0, 2)
    QSTEP(t6 + 1, rA1, rA0, 0, 1, 1, 0)
    QSTEP(t6 + 2, rA0, rA1, 1, 0, 2, 1)
    QSTEP(t6 + 3, rA1, rA0, 0, 1, 0, 2)
    QSTEP(t6 + 4, rA0, rA1, 1, 0, 1, 0)
    QSTEP(t6 + 5, rA1, rA0, 0, 1, 2, 1)
  }
  COMPUTE(0, 0);
  VMCNT(4);
  A_WRITE(rA1, 1);
  VMCNT(0);
  LGKM0(); BARRIER();
  COMPUTE(1, 1);

  if (z == 2) {
    const int b = (bm * 128) >> 11;
    const int s0 = (bm * 128) & 2047;
    bf16_t* vb = Vt + ((size_t)b * 1024 + bn * 256 + wn + l15) * 2048 + s0 + wm + lhi * 4;
#pragma unroll
    for (int j = 0; j < 8; ++j) {
      float bv2 = bias[bn * 256 + wn + j * 16 + l15];
#pragma unroll
      for (int i = 0; i < 4; ++i) {
        bf16x4 pk;
#pragma unroll
        for (int r = 0; r < 4; ++r) pk[r] = f2bf(acc[i][j][r] + bv2);
        *reinterpret_cast<bf16x4*>(vb + (size_t)(j * 16) * 2048 + i * 16) = pk;
      }
    }
  } else {
    bf16_t* O = (z == 0) ? Qp : Kp;
    const float scale = (z == 0) ? CSCALE : 1.0f;
#pragma unroll
    for (int i = 0; i < 4; ++i) {
#pragma unroll
      for (int j = 0; j < 8; ++j) {
        int n = bn * 256 + wn + j * 16 + l15;
        float bv2 = bias[n];
#pragma unroll
        for (int r = 0; r < 4; ++r) {
          int m = bm * 128 + wm + i * 16 + lhi * 4 + r;
          O[(size_t)m * 1024 + n] = f2bf((acc[i][j][r] + bv2) * scale);
        }
      }
    }
  }
#undef QSTEP
}

// ---------------- output GEMM: 128x256 tile, bf16 A, depth-2 counted-vmcnt (R10) ----------------
__global__ __launch_bounds__(256, 2) void gemm_o(
    const bf16_t* __restrict__ A, const bf16_t* __restrict__ Bw,
    const float* __restrict__ bias, float* __restrict__ Cout) {
  constexpr int K = 1024;
  __shared__ __align__(16) bf16_t As[3][128 * 32];
  __shared__ __align__(16) bf16_t Bs[3][256 * 32];
  const int tid = threadIdx.x;
  const int lane = tid & 63;
  const int wv_ = tid >> 6;
  const int wm = (wv_ & 1) * 64, wn = (wv_ >> 1) * 128;
  const int l15 = lane & 15, lhi = lane >> 4;
  const int bm = blockIdx.x, bn = blockIdx.y;
  const int rws = tid >> 2;
  const bf16_t* ga = A + (size_t)(bm * 128 + rws) * K + ((tid & 3) ^ (rws & 3)) * 8;
  const bf16_t* gb = Bw + (size_t)(bn * 256 + rws) * K + ((tid & 3) ^ (rws & 3)) * 8;
  f32x4 acc[4][8] = {};

  auto STAGE = [&](int t, int buf) {
#pragma unroll
    for (int c2 = 0; c2 < 2; ++c2)
      GLD_LDS(ga + (size_t)c2 * 64 * K + t * 32, (char*)&As[buf][0] + c2 * 4096 + wv_ * 1024);
#pragma unroll
    for (int c2 = 0; c2 < 4; ++c2)
      GLD_LDS(gb + (size_t)c2 * 64 * K + t * 32, (char*)&Bs[buf][0] + c2 * 4096 + wv_ * 1024);
  };
  auto COMPUTE = [&](int buf) {
    bf16x8 af[4], bfv[8];
#pragma unroll
    for (int i = 0; i < 4; ++i) {
      int arow = wm + i * 16 + l15;
      af[i] = *reinterpret_cast<const bf16x8*>(
          (const char*)&As[buf][0] + arow * 64 + ((lhi ^ (arow & 3)) * 16));
    }
#pragma unroll
    for (int j = 0; j < 8; ++j) {
      int br = wn + j * 16 + l15;
      bfv[j] = *reinterpret_cast<const bf16x8*>(
          (const char*)&Bs[buf][0] + br * 64 + ((lhi ^ (br & 3)) * 16));
    }
#pragma unroll
    for (int i = 0; i < 4; ++i)
#pragma unroll
      for (int j = 0; j < 8; ++j)
        acc[i][j] = __builtin_amdgcn_mfma_f32_16x16x32_bf16(af[i], bfv[j], acc[i][j], 0, 0, 0);
  };

  STAGE(0, 0);
  STAGE(1, 1);
#pragma unroll 1
  for (int tt = 0; tt < 30; tt += 3) {
    VMCNT(6); BARRIER(); COMPUTE(0); STAGE(tt + 2, 2);
    VMCNT(6); BARRIER(); COMPUTE(1); STAGE(tt + 3, 0);
    VMCNT(6); BARRIER(); COMPUTE(2); STAGE(tt + 4, 1);
  }
  VMCNT(6); BARRIER(); COMPUTE(0);
  VMCNT(0); BARRIER(); COMPUTE(1);

#pragma unroll
  for (int i = 0; i < 4; ++i)
#pragma unroll
    for (int j = 0; j < 8; ++j) {
      int n = bn * 256 + wn + j * 16 + l15;
      float bv2 = bias[n];
#pragma unroll
      for (int r = 0; r < 4; ++r) {
        int m = bm * 128 + wm + i * 16 + lhi * 4 + r;
        Cout[(size_t)m * 1024 + n] = acc[i][j][r] + bv2;
      }
    }
}

// ---------------- flash attention: exact round-5 structure (measured 115 us) ----------------
// 32 q-rows/wave, serial QK->SM->PV per tile, reg prefetch depth-1, 1 barrier/tile,
// osum-via-MFMA row sums, padded conflict-free LDS, unroll 2. Adaptations: Q pre-scaled
// (sub+exp2, THR=8 log2), rescale branch per-row-correct via shfl (never taken).
__global__ __launch_bounds__(256, 4) void attn_kernel(
    const bf16_t* __restrict__ Qp, const bf16_t* __restrict__ Kp,
    const bf16_t* __restrict__ Vt, const uint* __restrict__ maskbits,
    bf16_t* __restrict__ Xb) {
  constexpr int S = 2048, D = 1024;
  __shared__ __align__(16) bf16_t Ks[2][32][72];  // 144 B rows: 9-granule stride
  __shared__ __align__(16) bf16_t Vs[2][64][40];  // 80 B rows: 5-granule stride
  const int tid = threadIdx.x;
  const int wv_ = tid >> 6, lane = tid & 63;
  const int l31 = lane & 31, h = lane >> 5;
  const int blk = blockIdx.x;
  const int bh = blk & 63, qt4 = blk >> 6;
  const int b = bh >> 4, hd = bh & 15;
  const int q0 = qt4 * 128 + wv_ * 32;

  const int rK = tid >> 3, sK = tid & 7;  // K: 32 rows x 8 slots of 16B
  const int rV = tid >> 2, sV = tid & 3;  // V: 64 rows x 4 slots of 16B
  const bf16_t* gK = Kp + ((size_t)b * S + rK) * D + hd * 64 + sK * 8;
  const bf16_t* gV = Vt + ((size_t)b * 1024 + hd * 64 + rV) * (size_t)S + sV * 8;

  // Q as B-fragment (pre-scaled by CSCALE): col q = l31, rows d = 16c + 8h + j
  const bf16_t* qbase = Qp + (size_t)(b * S + q0 + l31) * D + hd * 64 + h * 8;
  bf16x8 qf[4];
#pragma unroll
  for (int c = 0; c < 4; ++c)
    qf[c] = *reinterpret_cast<const bf16x8*>(qbase + 16 * c);

  const uint* mbase = maskbits + q0 + l31;

  bf16x8 ones;
#pragma unroll
  for (int i = 0; i < 8; ++i) ones[i] = (bf16_t)1.0f;

  f32x16 o0 = {}, o1 = {}, osum = {};
  float mrun = 0.f;

  // prologue: stage tile 0
  {
    bf16x8 k0r = *reinterpret_cast<const bf16x8*>(gK);
    bf16x8 v0r = *reinterpret_cast<const bf16x8*>(gV);
    *reinterpret_cast<bf16x8*>(&Ks[0][rK][sK * 8]) = k0r;
    *reinterpret_cast<bf16x8*>(&Vs[0][rV][sV * 8]) = v0r;
    __syncthreads();
  }

#pragma unroll 2
  for (int t = 0; t < 64; ++t) {
    const int cur = t & 1, nxt = cur ^ 1;
    const bool pf = (t < 63);
    // ---- issue next-tile global loads (hidden under compute) ----
    bf16x8 kreg, vreg;
    if (pf) {
      kreg = *reinterpret_cast<const bf16x8*>(gK + (size_t)(t + 1) * 32 * D);
      vreg = *reinterpret_cast<const bf16x8*>(gV + (t + 1) * 32);
    }
    uint mbc = mbase[t * 2048];
    // ---- QK^T from LDS ----
    f32x16 s = {};
    __builtin_amdgcn_s_setprio(1);
#pragma unroll
    for (int c = 0; c < 4; ++c) {
      bf16x8 kf = *reinterpret_cast<const bf16x8*>(&Ks[cur][l31][h * 8 + 16 * c]);
      s = __builtin_amdgcn_mfma_f32_32x32x16_bf16(kf, qf[c], s, 0, 0, 0);
    }
    __builtin_amdgcn_s_setprio(0);
    // ---- softmax (log2 domain; Q pre-scaled) ----
    const uint mbh = mbc >> (h << 4);
    float a0 = fmaxf(fmaxf(s[0], s[1]), s[2]);
    float a1 = fmaxf(fmaxf(s[3], s[4]), s[5]);
    float a2 = fmaxf(fmaxf(s[6], s[7]), s[8]);
    float a3 = fmaxf(fmaxf(s[9], s[10]), s[11]);
    float a4 = fmaxf(fmaxf(s[12], s[13]), s[14]);
    float b0 = fmaxf(fmaxf(a0, a1), a2);
    float b1 = fmaxf(a3, a4);
    float mt = fmaxf(fmaxf(b0, b1), s[15]);
    mt = fmaxf(mt, __shfl_xor(mt, 32));
    if (!__all(mt - mrun <= 8.0f)) {  // defer-max safety; ~never taken
      float mnew = fmaxf(mrun, mt);
      float alpha = __builtin_amdgcn_exp2f(mrun - mnew);
#pragma unroll
      for (int r = 0; r < 16; ++r) {
        float ar = __shfl(alpha, (r & 3) + 8 * (r >> 2) + 4 * h);
        o0[r] *= ar; o1[r] *= ar; osum[r] *= ar;
      }
      mrun = mnew;
    }
    float p[16];
#pragma unroll
    for (int r = 0; r < 16; ++r) {
      float pv = __builtin_amdgcn_exp2f(s[r] - mrun);
      uint smask = (uint)__builtin_amdgcn_sbfe((int)mbh, r, 1);  // 0 or ~0
      p[r] = __builtin_bit_cast(float, __builtin_bit_cast(uint, pv) & smask);
    }
    // pack p -> bf16 dwords, rearrange into A-fragment via xor-32 exchange
    uint dw[8];
#pragma unroll
    for (int i = 0; i < 8; ++i) dw[i] = cvt_pk(p[2 * i], p[2 * i + 1]);
    uint e0 = (uint)__shfl_xor((int)(h ? dw[0] : dw[2]), 32);
    uint e1 = (uint)__shfl_xor((int)(h ? dw[1] : dw[3]), 32);
    uint e2 = (uint)__shfl_xor((int)(h ? dw[4] : dw[6]), 32);
    uint e3 = (uint)__shfl_xor((int)(h ? dw[5] : dw[7]), 32);
    uint4v ua0 = {h ? e0 : dw[0], h ? e1 : dw[1], h ? dw[2] : e0, h ? dw[3] : e1};
    uint4v ua1 = {h ? e2 : dw[4], h ? e3 : dw[5], h ? dw[6] : e2, h ? dw[7] : e3};
    bf16x8 pa0 = __builtin_bit_cast(bf16x8, ua0);
    bf16x8 pa1 = __builtin_bit_cast(bf16x8, ua1);
    // ---- PV + row-sum via MFMA-ones ----
    {
      bf16x8 v00 = *reinterpret_cast<const bf16x8*>(&Vs[cur][l31][h * 8]);
      bf16x8 v01 = *reinterpret_cast<const bf16x8*>(&Vs[cur][l31][16 + h * 8]);
      bf16x8 v10 = *reinterpret_cast<const bf16x8*>(&Vs[cur][32 + l31][h * 8]);
      bf16x8 v11 = *reinterpret_cast<const bf16x8*>(&Vs[cur][32 + l31][16 + h * 8]);
      __builtin_amdgcn_s_setprio(1);
      o0 = __builtin_amdgcn_mfma_f32_32x32x16_bf16(pa0, v00, o0, 0, 0, 0);
      o0 = __builtin_amdgcn_mfma_f32_32x32x16_bf16(pa1, v01, o0, 0, 0, 0);
      o1 = __builtin_amdgcn_mfma_f32_32x32x16_bf16(pa0, v10, o1, 0, 0, 0);
      o1 = __builtin_amdgcn_mfma_f32_32x32x16_bf16(pa1, v11, o1, 0, 0, 0);
      osum = __builtin_amdgcn_mfma_f32_32x32x16_bf16(pa0, ones, osum, 0, 0, 0);
      osum = __builtin_amdgcn_mfma_f32_32x32x16_bf16(pa1, ones, osum, 0, 0, 0);
      __builtin_amdgcn_s_setprio(0);
    }
    // ---- write staged tile t+1, one barrier per tile ----
    if (pf) {
      *reinterpret_cast<bf16x8*>(&Ks[nxt][rK][sK * 8]) = kreg;  // vmcnt wait lands here
      *reinterpret_cast<bf16x8*>(&Vs[nxt][rV][sV * 8]) = vreg;
      __syncthreads();
    }
  }
  // epilogue: osum[r] holds the row-sum for exactly o0[r]/o1[r]'s q-row
  bf16_t* xrow = Xb + (size_t)(b * S + q0) * D + hd * 64 + l31;
#pragma unroll
  for (int r = 0; r < 16; ++r) {
    int qrow = (r & 3) + 8 * (r >> 2) + 4 * h;
    float lr = __builtin_amdgcn_rcpf(osum[r]);
    xrow[(size_t)qrow * D] = f2bf(o0[r] * lr);
    xrow[(size_t)qrow * D + 32] = f2bf(o1[r] * lr);
  }
}

// ---------------- launch ----------------
extern "C" void kernel_launch(void* const* d_in, const int* in_sizes, int n_in,
                              void* d_out, int out_size, void* d_ws, size_t ws_size,
                              hipStream_t stream) {
  const float* q = (const float*)d_in[0];
  const float* k = (const float*)d_in[1];
  const float* v = (const float*)d_in[2];
  const int* mask = (const int*)d_in[3];
  const float* w_q = (const float*)d_in[4];
  const float* b_q = (const float*)d_in[5];
  const float* w_k = (const float*)d_in[6];
  const float* b_k = (const float*)d_in[7];
  const float* w_v = (const float*)d_in[8];
  const float* b_v = (const float*)d_in[9];
  const float* w_o = (const float*)d_in[10];
  const float* b_o = (const float*)d_in[11];

  char* ws = (char*)d_ws;
  const size_t SZ = (size_t)8192 * 1024 * 2;  // 16 MiB
  bf16_t* Qp = (bf16_t*)(ws + 0 * SZ);
  bf16_t* Kp = (bf16_t*)(ws + 1 * SZ);
  bf16_t* Vt = (bf16_t*)(ws + 2 * SZ);
  bf16_t* Xb = (bf16_t*)(ws + 3 * SZ);
  uint* maskB = (uint*)(ws + 4 * SZ);
  bf16_t* wqb = (bf16_t*)(ws + 4 * SZ + 8388608);
  bf16_t* wkb = wqb + 1048576;
  bf16_t* wvb = wkb + 1048576;
  bf16_t* wob = wvb + 1048576;

  cvt4_f2b<<<4096, 256, 0, stream>>>(w_q, w_k, w_v, w_o, wqb, wkb, wvb, wob);
  mask_bits_k<<<512, 256, 0, stream>>>(mask, maskB);

  dim3 g3(64, 4, 3);
  qkv_gemm<<<g3, 256, 0, stream>>>(q, k, v, wqb, wkb, wvb, b_q, b_k, b_v, Qp, Kp, Vt);
  attn_kernel<<<1024, 256, 0, stream>>>(Qp, Kp, Vt, maskB, Xb);
  gemm_o<<<dim3(64, 4), 256, 0, stream>>>(Xb, wob, b_o, (float*)d_out);
}

// Round 16
// 241.626 us; speedup vs baseline: 1.4436x; 1.4436x over previous
//
#include <hip/hip_runtime.h>

typedef __bf16 bf16_t;
typedef __bf16 bf16x4 __attribute__((ext_vector_type(4)));
typedef __bf16 bf16x8 __attribute__((ext_vector_type(8)));
typedef float f32x4 __attribute__((ext_vector_type(4)));
typedef float f32x16 __attribute__((ext_vector_type(16)));
typedef unsigned int uint;
typedef uint uint2v __attribute__((ext_vector_type(2)));
typedef uint uint4v __attribute__((ext_vector_type(4)));

#define CSCALE 0.18033688011112042f  // 0.125 * log2(e)

static __device__ __forceinline__ bf16_t f2bf(float f) {
  unsigned u = __builtin_bit_cast(unsigned, f);
  u = (u + 0x7fff + ((u >> 16) & 1)) >> 16;
  unsigned short h = (unsigned short)u;
  return __builtin_bit_cast(bf16_t, h);
}
static __device__ __forceinline__ uint cvt_pk(float a, float b) {
  uint r;
  asm("v_cvt_pk_bf16_f32 %0, %1, %2" : "=v"(r) : "v"(a), "v"(b));
  return r;
}

#define GLD_LDS(g, l) \
  __builtin_amdgcn_global_load_lds((const __attribute__((address_space(1))) void*)(g), \
                                   (__attribute__((address_space(3))) void*)(l), 16, 0, 0)
#define VMCNT(n) asm volatile("s_waitcnt vmcnt(" #n ")" ::: "memory")
#define LGKM0() asm volatile("s_waitcnt lgkmcnt(0)" ::: "memory")
#define BARRIER() do { __builtin_amdgcn_s_barrier(); __builtin_amdgcn_sched_barrier(0); } while (0)

// ---------------- conversion kernels ----------------
__global__ void cvt4_f2b(const float* __restrict__ a, const float* __restrict__ b,
                         const float* __restrict__ c, const float* __restrict__ d,
                         bf16_t* __restrict__ oa, bf16_t* __restrict__ ob,
                         bf16_t* __restrict__ oc, bf16_t* __restrict__ od) {
  int i = blockIdx.x * 256 + threadIdx.x;  // 4 * 262144
  const float* src = a;
  bf16_t* dst = oa;
  int w = i >> 18;
  i &= 262143;
  if (w == 1) { src = b; dst = ob; }
  else if (w == 2) { src = c; dst = oc; }
  else if (w == 3) { src = d; dst = od; }
  const float4 f = reinterpret_cast<const float4*>(src)[i];
  bf16x4 o;
  o[0] = f2bf(f.x); o[1] = f2bf(f.y); o[2] = f2bf(f.z); o[3] = f2bf(f.w);
  reinterpret_cast<bf16x4*>(dst)[i] = o;
}

__global__ void mask_bits_k(const int* __restrict__ m, uint* __restrict__ out) {
  int i = blockIdx.x * 256 + threadIdx.x;  // 131072
  int q = i & 2047, t = i >> 11;
  const int* mrow = m + (size_t)q * 2048 + t * 32;
  uint bits = 0;
#pragma unroll
  for (int j = 0; j < 16; ++j) {
    int r0 = (j & 3) + 8 * (j >> 2);
    bits |= (mrow[r0] ? 1u : 0u) << j;
    bits |= (mrow[r0 + 4] ? 1u : 0u) << (16 + j);
  }
  out[(size_t)t * 2048 + q] = bits;
}

// ---------------- merged QKV GEMM: 128x256 tile, bf16 LDS, reg-staged A (R10) ----------------
__global__ __launch_bounds__(256, 2) void qkv_gemm(
    const float* __restrict__ qA, const float* __restrict__ kA, const float* __restrict__ vA,
    const bf16_t* __restrict__ wq, const bf16_t* __restrict__ wk, const bf16_t* __restrict__ wv,
    const float* __restrict__ bq, const float* __restrict__ bk, const float* __restrict__ bv,
    bf16_t* __restrict__ Qp, bf16_t* __restrict__ Kp, bf16_t* __restrict__ Vt) {
  constexpr int K = 1024;
  __shared__ __align__(16) bf16_t AsB[2][128 * 32];   // 2 x 8 KB
  __shared__ __align__(16) bf16_t BsB[3][256 * 32];   // 3 x 16 KB
  const int z = blockIdx.z;
  const float* A = (z == 0) ? qA : (z == 1) ? kA : vA;
  const bf16_t* W = (z == 0) ? wq : (z == 1) ? wk : wv;
  const float* bias = (z == 0) ? bq : (z == 1) ? bk : bv;

  const int tid = threadIdx.x;
  const int lane = tid & 63;
  const int wv_ = tid >> 6;
  const int wm = (wv_ & 1) * 64, wn = (wv_ >> 1) * 128;
  const int l15 = lane & 15, lhi = lane >> 4;
  const int bm = blockIdx.x, bn = blockIdx.y;

  const int arow0 = tid >> 3;  // 0..31
  const int acol = tid & 7;    // 0..7
  const float* gA = A + (size_t)(bm * 128 + arow0) * K + acol * 4;
  const int brows = tid >> 2;
  const bf16_t* gB = W + (size_t)(bn * 256 + brows) * K + ((tid & 3) ^ (brows & 3)) * 8;

  f32x4 acc[4][8] = {};
  f32x4 rA0[4], rA1[4];

  auto A_LOAD = [&](int t, f32x4* R) {
#pragma unroll
    for (int L = 0; L < 4; ++L)
      R[L] = *reinterpret_cast<const f32x4*>(gA + (size_t)L * 32 * K + t * 32);
  };
  auto A_WRITE = [&](const f32x4* R, int buf) {
#pragma unroll
    for (int L = 0; L < 4; ++L) {
      int row = arow0 + L * 32;
      uint2v u;
      u[0] = cvt_pk(R[L][0], R[L][1]);
      u[1] = cvt_pk(R[L][2], R[L][3]);
      char* p = (char*)&AsB[buf][0] + row * 64 + (((acol >> 1) ^ (row & 3)) * 16) + (acol & 1) * 8;
      *reinterpret_cast<uint2v*>(p) = u;
    }
  };
  auto B_STAGE = [&](int t, int buf) {
#pragma unroll
    for (int c2 = 0; c2 < 4; ++c2)
      GLD_LDS(gB + (size_t)c2 * 64 * K + t * 32, (char*)&BsB[buf][0] + c2 * 4096 + wv_ * 1024);
  };
  auto COMPUTE = [&](int ba, int bb) {
    bf16x8 af[4], bfv[8];
#pragma unroll
    for (int i = 0; i < 4; ++i) {
      int arow = wm + i * 16 + l15;
      af[i] = *reinterpret_cast<const bf16x8*>(
          (const char*)&AsB[ba][0] + arow * 64 + ((lhi ^ (arow & 3)) * 16));
    }
#pragma unroll
    for (int j = 0; j < 8; ++j) {
      int br = wn + j * 16 + l15;
      bfv[j] = *reinterpret_cast<const bf16x8*>(
          (const char*)&BsB[bb][0] + br * 64 + ((lhi ^ (br & 3)) * 16));
    }
#pragma unroll
    for (int i = 0; i < 4; ++i)
#pragma unroll
      for (int j = 0; j < 8; ++j)
        acc[i][j] = __builtin_amdgcn_mfma_f32_16x16x32_bf16(af[i], bfv[j], acc[i][j], 0, 0, 0);
  };

#define QSTEP(T, RL, RW, BAW, BAC, BBC, BBS) \
  A_LOAD((T) + 2, RL); B_STAGE((T) + 2, BBS); \
  COMPUTE(BAC, BBC); \
  VMCNT(8); \
  A_WRITE(RW, BAW); \
  LGKM0(); BARRIER();

  A_LOAD(0, rA0); B_STAGE(0, 0);
  A_LOAD(1, rA1); B_STAGE(1, 1);
  VMCNT(8);
  A_WRITE(rA0, 0);
  LGKM0(); BARRIER();

#pragma unroll 1
  for (int t6 = 0; t6 < 30; t6 += 6) {
    QSTEP(t6 + 0, rA0, rA1, 1, 0, 0, 2)
    QSTEP(t6 + 1, rA1, rA0, 0, 1, 1, 0)
    QSTEP(t6 + 2, rA0, rA1, 1, 0, 2, 1)
    QSTEP(t6 + 3, rA1, rA0, 0, 1, 0, 2)
    QSTEP(t6 + 4, rA0, rA1, 1, 0, 1, 0)
    QSTEP(t6 + 5, rA1, rA0, 0, 1, 2, 1)
  }
  COMPUTE(0, 0);
  VMCNT(4);
  A_WRITE(rA1, 1);
  VMCNT(0);
  LGKM0(); BARRIER();
  COMPUTE(1, 1);

  if (z == 2) {
    const int b = (bm * 128) >> 11;
    const int s0 = (bm * 128) & 2047;
    bf16_t* vb = Vt + ((size_t)b * 1024 + bn * 256 + wn + l15) * 2048 + s0 + wm + lhi * 4;
#pragma unroll
    for (int j = 0; j < 8; ++j) {
      float bv2 = bias[bn * 256 + wn + j * 16 + l15];
#pragma unroll
      for (int i = 0; i < 4; ++i) {
        bf16x4 pk;
#pragma unroll
        for (int r = 0; r < 4; ++r) pk[r] = f2bf(acc[i][j][r] + bv2);
        *reinterpret_cast<bf16x4*>(vb + (size_t)(j * 16) * 2048 + i * 16) = pk;
      }
    }
  } else {
    bf16_t* O = (z == 0) ? Qp : Kp;
    const float scale = (z == 0) ? CSCALE : 1.0f;
#pragma unroll
    for (int i = 0; i < 4; ++i) {
#pragma unroll
      for (int j = 0; j < 8; ++j) {
        int n = bn * 256 + wn + j * 16 + l15;
        float bv2 = bias[n];
#pragma unroll
        for (int r = 0; r < 4; ++r) {
          int m = bm * 128 + wm + i * 16 + lhi * 4 + r;
          O[(size_t)m * 1024 + n] = f2bf((acc[i][j][r] + bv2) * scale);
        }
      }
    }
  }
#undef QSTEP
}

// ---------------- output GEMM: 128x256 tile, bf16 A, depth-2 counted-vmcnt (R10) ----------------
__global__ __launch_bounds__(256, 2) void gemm_o(
    const bf16_t* __restrict__ A, const bf16_t* __restrict__ Bw,
    const float* __restrict__ bias, float* __restrict__ Cout) {
  constexpr int K = 1024;
  __shared__ __align__(16) bf16_t As[3][128 * 32];
  __shared__ __align__(16) bf16_t Bs[3][256 * 32];
  const int tid = threadIdx.x;
  const int lane = tid & 63;
  const int wv_ = tid >> 6;
  const int wm = (wv_ & 1) * 64, wn = (wv_ >> 1) * 128;
  const int l15 = lane & 15, lhi = lane >> 4;
  const int bm = blockIdx.x, bn = blockIdx.y;
  const int rws = tid >> 2;
  const bf16_t* ga = A + (size_t)(bm * 128 + rws) * K + ((tid & 3) ^ (rws & 3)) * 8;
  const bf16_t* gb = Bw + (size_t)(bn * 256 + rws) * K + ((tid & 3) ^ (rws & 3)) * 8;
  f32x4 acc[4][8] = {};

  auto STAGE = [&](int t, int buf) {
#pragma unroll
    for (int c2 = 0; c2 < 2; ++c2)
      GLD_LDS(ga + (size_t)c2 * 64 * K + t * 32, (char*)&As[buf][0] + c2 * 4096 + wv_ * 1024);
#pragma unroll
    for (int c2 = 0; c2 < 4; ++c2)
      GLD_LDS(gb + (size_t)c2 * 64 * K + t * 32, (char*)&Bs[buf][0] + c2 * 4096 + wv_ * 1024);
  };
  auto COMPUTE = [&](int buf) {
    bf16x8 af[4], bfv[8];
#pragma unroll
    for (int i = 0; i < 4; ++i) {
      int arow = wm + i * 16 + l15;
      af[i] = *reinterpret_cast<const bf16x8*>(
          (const char*)&As[buf][0] + arow * 64 + ((lhi ^ (arow & 3)) * 16));
    }
#pragma unroll
    for (int j = 0; j < 8; ++j) {
      int br = wn + j * 16 + l15;
      bfv[j] = *reinterpret_cast<const bf16x8*>(
          (const char*)&Bs[buf][0] + br * 64 + ((lhi ^ (br & 3)) * 16));
    }
#pragma unroll
    for (int i = 0; i < 4; ++i)
#pragma unroll
      for (int j = 0; j < 8; ++j)
        acc[i][j] = __builtin_amdgcn_mfma_f32_16x16x32_bf16(af[i], bfv[j], acc[i][j], 0, 0, 0);
  };

  STAGE(0, 0);
  STAGE(1, 1);
#pragma unroll 1
  for (int tt = 0; tt < 30; tt += 3) {
    VMCNT(6); BARRIER(); COMPUTE(0); STAGE(tt + 2, 2);
    VMCNT(6); BARRIER(); COMPUTE(1); STAGE(tt + 3, 0);
    VMCNT(6); BARRIER(); COMPUTE(2); STAGE(tt + 4, 1);
  }
  VMCNT(6); BARRIER(); COMPUTE(0);
  VMCNT(0); BARRIER(); COMPUTE(1);

#pragma unroll
  for (int i = 0; i < 4; ++i)
#pragma unroll
    for (int j = 0; j < 8; ++j) {
      int n = bn * 256 + wn + j * 16 + l15;
      float bv2 = bias[n];
#pragma unroll
      for (int r = 0; r < 4; ++r) {
        int m = bm * 128 + wm + i * 16 + lhi * 4 + r;
        Cout[(size_t)m * 1024 + n] = acc[i][j][r] + bv2;
      }
    }
}

// ---------------- flash attention: R14 structure, NO s_setprio (m190: negative in
// barrier-synced multi-wave blocks; m191's + was 1-wave-block-specific) ----------------
static __device__ __forceinline__ void qk2(const bf16_t* Kbuf, const bf16x8 qfA[4],
                                           const bf16x8 qfB[4], int l31, int h,
                                           f32x16& sA, f32x16& sB) {
  sA = {}; sB = {};
#pragma unroll
  for (int c = 0; c < 4; ++c) {
    bf16x8 kf = *reinterpret_cast<const bf16x8*>(Kbuf + l31 * 72 + h * 8 + 16 * c);
    sA = __builtin_amdgcn_mfma_f32_32x32x16_bf16(kf, qfA[c], sA, 0, 0, 0);
    sB = __builtin_amdgcn_mfma_f32_32x32x16_bf16(kf, qfB[c], sB, 0, 0, 0);
  }
}

static __device__ __forceinline__ void softmax_tile(
    const f32x16& sv, uint mb, int h, f32x16& o0, f32x16& o1,
    float& mrun, float& lsum, bf16x8& pa0, bf16x8& pa1) {
  const uint mbh = mb >> (h << 4);
  float a0 = fmaxf(fmaxf(sv[0], sv[1]), sv[2]);
  float a1 = fmaxf(fmaxf(sv[3], sv[4]), sv[5]);
  float a2 = fmaxf(fmaxf(sv[6], sv[7]), sv[8]);
  float a3 = fmaxf(fmaxf(sv[9], sv[10]), sv[11]);
  float a4 = fmaxf(fmaxf(sv[12], sv[13]), sv[14]);
  float b0 = fmaxf(fmaxf(a0, a1), a2);
  float mt = fmaxf(fmaxf(b0, fmaxf(a3, a4)), sv[15]);
  if (!__all(mt - mrun <= 8.0f)) {  // defer-max safety (log2 units); ~never taken
    float mtf = fmaxf(mt, __shfl_xor(mt, 32));
    float mnew = fmaxf(mrun, mtf);
    float alpha = __builtin_amdgcn_exp2f(mrun - mnew);
    lsum *= alpha;
#pragma unroll
    for (int r = 0; r < 16; ++r) {
      float ar = __shfl(alpha, (r & 3) + 8 * (r >> 2) + 4 * h);
      o0[r] *= ar; o1[r] *= ar;
    }
    mrun = mnew;
  }
  float p[16];
#pragma unroll
  for (int r = 0; r < 16; ++r) {
    float pv = __builtin_amdgcn_exp2f(sv[r] - mrun);
    uint smask = (uint)__builtin_amdgcn_sbfe((int)mbh, r, 1);  // 0 or ~0
    p[r] = __builtin_bit_cast(float, __builtin_bit_cast(uint, pv) & smask);
  }
  float t0 = p[0] + p[1], t1 = p[2] + p[3], t2 = p[4] + p[5], t3 = p[6] + p[7];
  float t4 = p[8] + p[9], t5 = p[10] + p[11], t6 = p[12] + p[13], t7 = p[14] + p[15];
  t0 += t1; t2 += t3; t4 += t5; t6 += t7;
  lsum += (t0 + t2) + (t4 + t6);  // per-lane half-row sum; cross-half deferred
  uint dw[8];
#pragma unroll
  for (int i = 0; i < 8; ++i) dw[i] = cvt_pk(p[2 * i], p[2 * i + 1]);
  uint e0 = (uint)__shfl_xor((int)(h ? dw[0] : dw[2]), 32);
  uint e1 = (uint)__shfl_xor((int)(h ? dw[1] : dw[3]), 32);
  uint e2 = (uint)__shfl_xor((int)(h ? dw[4] : dw[6]), 32);
  uint e3 = (uint)__shfl_xor((int)(h ? dw[5] : dw[7]), 32);
  uint4v ua0 = {h ? e0 : dw[0], h ? e1 : dw[1], h ? dw[2] : e0, h ? dw[3] : e1};
  uint4v ua1 = {h ? e2 : dw[4], h ? e3 : dw[5], h ? dw[6] : e2, h ? dw[7] : e3};
  pa0 = __builtin_bit_cast(bf16x8, ua0);
  pa1 = __builtin_bit_cast(bf16x8, ua1);
}

static __device__ __forceinline__ void pv2(const bf16_t* Vbuf,
                                           bf16x8 paA0, bf16x8 paA1, bf16x8 paB0, bf16x8 paB1,
                                           int l31, int h,
                                           f32x16& oA0, f32x16& oA1, f32x16& oB0, f32x16& oB1) {
  bf16x8 v00 = *reinterpret_cast<const bf16x8*>(Vbuf + l31 * 40 + h * 8);
  bf16x8 v01 = *reinterpret_cast<const bf16x8*>(Vbuf + l31 * 40 + 16 + h * 8);
  bf16x8 v10 = *reinterpret_cast<const bf16x8*>(Vbuf + (32 + l31) * 40 + h * 8);
  bf16x8 v11 = *reinterpret_cast<const bf16x8*>(Vbuf + (32 + l31) * 40 + 16 + h * 8);
  oA0 = __builtin_amdgcn_mfma_f32_32x32x16_bf16(paA0, v00, oA0, 0, 0, 0);
  oA0 = __builtin_amdgcn_mfma_f32_32x32x16_bf16(paA1, v01, oA0, 0, 0, 0);
  oA1 = __builtin_amdgcn_mfma_f32_32x32x16_bf16(paA0, v10, oA1, 0, 0, 0);
  oA1 = __builtin_amdgcn_mfma_f32_32x32x16_bf16(paA1, v11, oA1, 0, 0, 0);
  oB0 = __builtin_amdgcn_mfma_f32_32x32x16_bf16(paB0, v00, oB0, 0, 0, 0);
  oB0 = __builtin_amdgcn_mfma_f32_32x32x16_bf16(paB1, v01, oB0, 0, 0, 0);
  oB1 = __builtin_amdgcn_mfma_f32_32x32x16_bf16(paB0, v10, oB1, 0, 0, 0);
  oB1 = __builtin_amdgcn_mfma_f32_32x32x16_bf16(paB1, v11, oB1, 0, 0, 0);
}

// 256-thread blocks (4 waves x 64 q-rows = 256 q/block); grid 512 = 8 q-tiles x 64 bh.
__global__ __launch_bounds__(256, 2) void attn_kernel(
    const bf16_t* __restrict__ Qp, const bf16_t* __restrict__ Kp,
    const bf16_t* __restrict__ Vt, const uint* __restrict__ maskbits,
    bf16_t* __restrict__ Xb) {
  constexpr int S = 2048, D = 1024;
  __shared__ __align__(16) bf16_t Ks[2][32][72];  // 144 B rows: 9-granule stride
  __shared__ __align__(16) bf16_t Vs[2][64][40];  // 80 B rows: 5-granule stride
  const int tid = threadIdx.x;
  const int wv_ = tid >> 6, lane = tid & 63;
  const int l31 = lane & 31, h = lane >> 5;
  const int blk = blockIdx.x;                     // 512 blocks
  const int bh = blk & 63, qt = blk >> 6;         // qt 0..7
  const int b = bh >> 4, hd = bh & 15;
  const int q0 = qt * 256 + wv_ * 64;             // wave owns q0..q0+63

  const int rK = tid >> 3, sK = tid & 7;
  const int rV = tid >> 2, sV = tid & 3;
  const bf16_t* gK = Kp + ((size_t)b * S + rK) * D + hd * 64 + sK * 8;
  const bf16_t* gV = Vt + ((size_t)b * 1024 + hd * 64 + rV) * (size_t)S + sV * 8;
  bf16_t* wK0 = &Ks[0][rK][sK * 8];
  bf16_t* wK1 = &Ks[1][rK][sK * 8];
  bf16_t* wV0 = &Vs[0][rV][sV * 8];
  bf16_t* wV1 = &Vs[1][rV][sV * 8];

  // Q fragments: A = cols q0+l31, B = cols q0+32+l31; rows d = 16c + 8h + j
  const bf16_t* qbase = Qp + (size_t)(b * S + q0 + l31) * D + hd * 64 + h * 8;
  bf16x8 qfA[4], qfB[4];
#pragma unroll
  for (int c = 0; c < 4; ++c) {
    qfA[c] = *reinterpret_cast<const bf16x8*>(qbase + 16 * c);
    qfB[c] = *reinterpret_cast<const bf16x8*>(qbase + (size_t)32 * D + 16 * c);
  }

  const uint* mbase = maskbits + q0 + l31;

  f32x16 oA0 = {}, oA1 = {}, oB0 = {}, oB1 = {};
  float mrunA = 0.f, lsumA = 0.f, mrunB = 0.f, lsumB = 0.f;
  bf16x8 paA0, paA1, paB0, paB1;

  // prologue: stage K(0)->Ks0, K(1)->Ks1, V(0)->Vs0; QK(0); SM(0)
  {
    bf16x8 k0 = *reinterpret_cast<const bf16x8*>(gK);
    bf16x8 k1 = *reinterpret_cast<const bf16x8*>(gK + (size_t)32 * D);
    bf16x8 v0 = *reinterpret_cast<const bf16x8*>(gV);
    *reinterpret_cast<bf16x8*>(wK0) = k0;
    *reinterpret_cast<bf16x8*>(wK1) = k1;
    *reinterpret_cast<bf16x8*>(wV0) = v0;
  }
  uint mbA = mbase[0], mbB = mbase[32];
  __syncthreads();
  {
    f32x16 sA, sB;
    qk2(&Ks[0][0][0], qfA, qfB, l31, h, sA, sB);
    softmax_tile(sA, mbA, h, oA0, oA1, mrunA, lsumA, paA0, paA1);
    softmax_tile(sB, mbB, h, oB0, oB1, mrunB, lsumB, paB0, paB1);
  }

  auto body = [&](int j, bf16_t* wK_st, bf16_t* wV_st, const bf16_t* Kq,
                  const bf16_t* Vp, bool stageK) {
    bf16x8 kreg, vreg;
    if (stageK) kreg = *reinterpret_cast<const bf16x8*>(gK + (size_t)(j + 2) * 32 * D);
    vreg = *reinterpret_cast<const bf16x8*>(gV + (size_t)(j + 1) * 32);
    uint mnA = mbase[(size_t)(j + 1) * 2048];
    uint mnB = mbase[(size_t)(j + 1) * 2048 + 32];
    f32x16 sA, sB;
    qk2(Kq, qfA, qfB, l31, h, sA, sB);                          // QK(j+1)
    pv2(Vp, paA0, paA1, paB0, paB1, l31, h, oA0, oA1, oB0, oB1); // PV(j)
    softmax_tile(sA, mnA, h, oA0, oA1, mrunA, lsumA, paA0, paA1); // SM(j+1)
    softmax_tile(sB, mnB, h, oB0, oB1, mrunB, lsumB, paB0, paB1);
    if (stageK) *reinterpret_cast<bf16x8*>(wK_st) = kreg;        // vmcnt wait lands here
    *reinterpret_cast<bf16x8*>(wV_st) = vreg;
    __syncthreads();
  };

#pragma unroll 1
  for (int jj = 0; jj < 31; ++jj) {
    const int j = 2 * jj;
    body(j,     wK0, wV1, &Ks[1][0][0], &Vs[0][0][0], true);
    body(j + 1, wK1, wV0, &Ks[0][0][0], &Vs[1][0][0], true);
  }
  body(62, wK0, wV1, &Ks[1][0][0], &Vs[0][0][0], false);
  // epilogue: PV(63)
  pv2(&Vs[1][0][0], paA0, paA1, paB0, paB1, l31, h, oA0, oA1, oB0, oB1);

  // finish row sums (one cross-half exchange each), normalize, store
  lsumA += __shfl_xor(lsumA, 32);
  lsumB += __shfl_xor(lsumB, 32);
  float linvA = __builtin_amdgcn_rcpf(lsumA);
  float linvB = __builtin_amdgcn_rcpf(lsumB);
  bf16_t* xrow = Xb + (size_t)(b * S + q0) * D + hd * 64 + l31;
#pragma unroll
  for (int r = 0; r < 16; ++r) {
    int qrow = (r & 3) + 8 * (r >> 2) + 4 * h;
    float lrA = __shfl(linvA, qrow);
    float lrB = __shfl(linvB, qrow);
    xrow[(size_t)qrow * D] = f2bf(oA0[r] * lrA);
    xrow[(size_t)qrow * D + 32] = f2bf(oA1[r] * lrA);
    xrow[(size_t)(qrow + 32) * D] = f2bf(oB0[r] * lrB);
    xrow[(size_t)(qrow + 32) * D + 32] = f2bf(oB1[r] * lrB);
  }
}

// ---------------- launch ----------------
extern "C" void kernel_launch(void* const* d_in, const int* in_sizes, int n_in,
                              void* d_out, int out_size, void* d_ws, size_t ws_size,
                              hipStream_t stream) {
  const float* q = (const float*)d_in[0];
  const float* k = (const float*)d_in[1];
  const float* v = (const float*)d_in[2];
  const int* mask = (const int*)d_in[3];
  const float* w_q = (const float*)d_in[4];
  const float* b_q = (const float*)d_in[5];
  const float* w_k = (const float*)d_in[6];
  const float* b_k = (const float*)d_in[7];
  const float* w_v = (const float*)d_in[8];
  const float* b_v = (const float*)d_in[9];
  const float* w_o = (const float*)d_in[10];
  const float* b_o = (const float*)d_in[11];

  char* ws = (char*)d_ws;
  const size_t SZ = (size_t)8192 * 1024 * 2;  // 16 MiB
  bf16_t* Qp = (bf16_t*)(ws + 0 * SZ);
  bf16_t* Kp = (bf16_t*)(ws + 1 * SZ);
  bf16_t* Vt = (bf16_t*)(ws + 2 * SZ);
  bf16_t* Xb = (bf16_t*)(ws + 3 * SZ);
  uint* maskB = (uint*)(ws + 4 * SZ);
  bf16_t* wqb = (bf16_t*)(ws + 4 * SZ + 8388608);
  bf16_t* wkb = wqb + 1048576;
  bf16_t* wvb = wkb + 1048576;
  bf16_t* wob = wvb + 1048576;

  cvt4_f2b<<<4096, 256, 0, stream>>>(w_q, w_k, w_v, w_o, wqb, wkb, wvb, wob);
  mask_bits_k<<<512, 256, 0, stream>>>(mask, maskB);

  dim3 g3(64, 4, 3);
  qkv_gemm<<<g3, 256, 0, stream>>>(q, k, v, wqb, wkb, wvb, b_q, b_k, b_v, Qp, Kp, Vt);
  attn_kernel<<<512, 256, 0, stream>>>(Qp, Kp, Vt, maskB, Xb);
  gemm_o<<<dim3(64, 4), 256, 0, stream>>>(Xb, wob, b_o, (float*)d_out);
}

// Round 17
// 225.780 us; speedup vs baseline: 1.5449x; 1.0702x over previous
//
#include <hip/hip_runtime.h>

typedef __bf16 bf16_t;
typedef __bf16 bf16x4 __attribute__((ext_vector_type(4)));
typedef __bf16 bf16x8 __attribute__((ext_vector_type(8)));
typedef float f32x4 __attribute__((ext_vector_type(4)));
typedef float f32x16 __attribute__((ext_vector_type(16)));
typedef unsigned int uint;
typedef uint uint2v __attribute__((ext_vector_type(2)));
typedef uint uint4v __attribute__((ext_vector_type(4)));

#define CSCALE 0.18033688011112042f  // 0.125 * log2(e)

static __device__ __forceinline__ bf16_t f2bf(float f) {
  unsigned u = __builtin_bit_cast(unsigned, f);
  u = (u + 0x7fff + ((u >> 16) & 1)) >> 16;
  unsigned short h = (unsigned short)u;
  return __builtin_bit_cast(bf16_t, h);
}
static __device__ __forceinline__ uint cvt_pk(float a, float b) {
  uint r;
  asm("v_cvt_pk_bf16_f32 %0, %1, %2" : "=v"(r) : "v"(a), "v"(b));
  return r;
}

#define GLD_LDS(g, l) \
  __builtin_amdgcn_global_load_lds((const __attribute__((address_space(1))) void*)(g), \
                                   (__attribute__((address_space(3))) void*)(l), 16, 0, 0)
#define VMCNT(n) asm volatile("s_waitcnt vmcnt(" #n ")" ::: "memory")
#define LGKM0() asm volatile("s_waitcnt lgkmcnt(0)" ::: "memory")
#define BARRIER() do { __builtin_amdgcn_s_barrier(); __builtin_amdgcn_sched_barrier(0); } while (0)

// ---------------- conversion kernels ----------------
__global__ void cvt4_f2b(const float* __restrict__ a, const float* __restrict__ b,
                         const float* __restrict__ c, const float* __restrict__ d,
                         bf16_t* __restrict__ oa, bf16_t* __restrict__ ob,
                         bf16_t* __restrict__ oc, bf16_t* __restrict__ od) {
  int i = blockIdx.x * 256 + threadIdx.x;  // 4 * 262144
  const float* src = a;
  bf16_t* dst = oa;
  int w = i >> 18;
  i &= 262143;
  if (w == 1) { src = b; dst = ob; }
  else if (w == 2) { src = c; dst = oc; }
  else if (w == 3) { src = d; dst = od; }
  const float4 f = reinterpret_cast<const float4*>(src)[i];
  bf16x4 o;
  o[0] = f2bf(f.x); o[1] = f2bf(f.y); o[2] = f2bf(f.z); o[3] = f2bf(f.w);
  reinterpret_cast<bf16x4*>(dst)[i] = o;
}

__global__ void mask_bits_k(const int* __restrict__ m, uint* __restrict__ out) {
  int i = blockIdx.x * 256 + threadIdx.x;  // 131072
  int q = i & 2047, t = i >> 11;
  const int* mrow = m + (size_t)q * 2048 + t * 32;
  uint bits = 0;
#pragma unroll
  for (int j = 0; j < 16; ++j) {
    int r0 = (j & 3) + 8 * (j >> 2);
    bits |= (mrow[r0] ? 1u : 0u) << j;
    bits |= (mrow[r0 + 4] ? 1u : 0u) << (16 + j);
  }
  out[(size_t)t * 2048 + q] = bits;
}

// ---------------- merged QKV GEMM: 128x256 tile, bf16 LDS, reg-staged A (R10) ----------------
__global__ __launch_bounds__(256, 2) void qkv_gemm(
    const float* __restrict__ qA, const float* __restrict__ kA, const float* __restrict__ vA,
    const bf16_t* __restrict__ wq, const bf16_t* __restrict__ wk, const bf16_t* __restrict__ wv,
    const float* __restrict__ bq, const float* __restrict__ bk, const float* __restrict__ bv,
    bf16_t* __restrict__ Qp, bf16_t* __restrict__ Kp, bf16_t* __restrict__ Vt) {
  constexpr int K = 1024;
  __shared__ __align__(16) bf16_t AsB[2][128 * 32];   // 2 x 8 KB
  __shared__ __align__(16) bf16_t BsB[3][256 * 32];   // 3 x 16 KB
  const int z = blockIdx.z;
  const float* A = (z == 0) ? qA : (z == 1) ? kA : vA;
  const bf16_t* W = (z == 0) ? wq : (z == 1) ? wk : wv;
  const float* bias = (z == 0) ? bq : (z == 1) ? bk : bv;

  const int tid = threadIdx.x;
  const int lane = tid & 63;
  const int wv_ = tid >> 6;
  const int wm = (wv_ & 1) * 64, wn = (wv_ >> 1) * 128;
  const int l15 = lane & 15, lhi = lane >> 4;
  const int bm = blockIdx.x, bn = blockIdx.y;

  const int arow0 = tid >> 3;  // 0..31
  const int acol = tid & 7;    // 0..7
  const float* gA = A + (size_t)(bm * 128 + arow0) * K + acol * 4;
  const int brows = tid >> 2;
  const bf16_t* gB = W + (size_t)(bn * 256 + brows) * K + ((tid & 3) ^ (brows & 3)) * 8;

  f32x4 acc[4][8] = {};
  f32x4 rA0[4], rA1[4];

  auto A_LOAD = [&](int t, f32x4* R) {
#pragma unroll
    for (int L = 0; L < 4; ++L)
      R[L] = *reinterpret_cast<const f32x4*>(gA + (size_t)L * 32 * K + t * 32);
  };
  auto A_WRITE = [&](const f32x4* R, int buf) {
#pragma unroll
    for (int L = 0; L < 4; ++L) {
      int row = arow0 + L * 32;
      uint2v u;
      u[0] = cvt_pk(R[L][0], R[L][1]);
      u[1] = cvt_pk(R[L][2], R[L][3]);
      char* p = (char*)&AsB[buf][0] + row * 64 + (((acol >> 1) ^ (row & 3)) * 16) + (acol & 1) * 8;
      *reinterpret_cast<uint2v*>(p) = u;
    }
  };
  auto B_STAGE = [&](int t, int buf) {
#pragma unroll
    for (int c2 = 0; c2 < 4; ++c2)
      GLD_LDS(gB + (size_t)c2 * 64 * K + t * 32, (char*)&BsB[buf][0] + c2 * 4096 + wv_ * 1024);
  };
  auto COMPUTE = [&](int ba, int bb) {
    bf16x8 af[4], bfv[8];
#pragma unroll
    for (int i = 0; i < 4; ++i) {
      int arow = wm + i * 16 + l15;
      af[i] = *reinterpret_cast<const bf16x8*>(
          (const char*)&AsB[ba][0] + arow * 64 + ((lhi ^ (arow & 3)) * 16));
    }
#pragma unroll
    for (int j = 0; j < 8; ++j) {
      int br = wn + j * 16 + l15;
      bfv[j] = *reinterpret_cast<const bf16x8*>(
          (const char*)&BsB[bb][0] + br * 64 + ((lhi ^ (br & 3)) * 16));
    }
#pragma unroll
    for (int i = 0; i < 4; ++i)
#pragma unroll
      for (int j = 0; j < 8; ++j)
        acc[i][j] = __builtin_amdgcn_mfma_f32_16x16x32_bf16(af[i], bfv[j], acc[i][j], 0, 0, 0);
  };

#define QSTEP(T, RL, RW, BAW, BAC, BBC, BBS) \
  A_LOAD((T) + 2, RL); B_STAGE((T) + 2, BBS); \
  COMPUTE(BAC, BBC); \
  VMCNT(8); \
  A_WRITE(RW, BAW); \
  LGKM0(); BARRIER();

  A_LOAD(0, rA0); B_STAGE(0, 0);
  A_LOAD(1, rA1); B_STAGE(1, 1);
  VMCNT(8);
  A_WRITE(rA0, 0);
  LGKM0(); BARRIER();

#pragma unroll 1
  for (int t6 = 0; t6 < 30; t6 += 6) {
    QSTEP(t6 + 0, rA0, rA1, 1, 0, 0, 2)
    QSTEP(t6 + 1, rA1, rA0, 0, 1, 1, 0)
    QSTEP(t6 + 2, rA0, rA1, 1, 0, 2, 1)
    QSTEP(t6 + 3, rA1, rA0, 0, 1, 0, 2)
    QSTEP(t6 + 4, rA0, rA1, 1, 0, 1, 0)
    QSTEP(t6 + 5, rA1, rA0, 0, 1, 2, 1)
  }
  COMPUTE(0, 0);
  VMCNT(4);
  A_WRITE(rA1, 1);
  VMCNT(0);
  LGKM0(); BARRIER();
  COMPUTE(1, 1);

  if (z == 2) {
    const int b = (bm * 128) >> 11;
    const int s0 = (bm * 128) & 2047;
    bf16_t* vb = Vt + ((size_t)b * 1024 + bn * 256 + wn + l15) * 2048 + s0 + wm + lhi * 4;
#pragma unroll
    for (int j = 0; j < 8; ++j) {
      float bv2 = bias[bn * 256 + wn + j * 16 + l15];
#pragma unroll
      for (int i = 0; i < 4; ++i) {
        bf16x4 pk;
#pragma unroll
        for (int r = 0; r < 4; ++r) pk[r] = f2bf(acc[i][j][r] + bv2);
        *reinterpret_cast<bf16x4*>(vb + (size_t)(j * 16) * 2048 + i * 16) = pk;
      }
    }
  } else {
    bf16_t* O = (z == 0) ? Qp : Kp;
    const float scale = (z == 0) ? CSCALE : 1.0f;
#pragma unroll
    for (int i = 0; i < 4; ++i) {
#pragma unroll
      for (int j = 0; j < 8; ++j) {
        int n = bn * 256 + wn + j * 16 + l15;
        float bv2 = bias[n];
#pragma unroll
        for (int r = 0; r < 4; ++r) {
          int m = bm * 128 + wm + i * 16 + lhi * 4 + r;
          O[(size_t)m * 1024 + n] = f2bf((acc[i][j][r] + bv2) * scale);
        }
      }
    }
  }
#undef QSTEP
}

// ---------------- output GEMM: 128x256 tile, bf16 A, depth-2 counted-vmcnt (R10) ----------------
__global__ __launch_bounds__(256, 2) void gemm_o(
    const bf16_t* __restrict__ A, const bf16_t* __restrict__ Bw,
    const float* __restrict__ bias, float* __restrict__ Cout) {
  constexpr int K = 1024;
  __shared__ __align__(16) bf16_t As[3][128 * 32];
  __shared__ __align__(16) bf16_t Bs[3][256 * 32];
  const int tid = threadIdx.x;
  const int lane = tid & 63;
  const int wv_ = tid >> 6;
  const int wm = (wv_ & 1) * 64, wn = (wv_ >> 1) * 128;
  const int l15 = lane & 15, lhi = lane >> 4;
  const int bm = blockIdx.x, bn = blockIdx.y;
  const int rws = tid >> 2;
  const bf16_t* ga = A + (size_t)(bm * 128 + rws) * K + ((tid & 3) ^ (rws & 3)) * 8;
  const bf16_t* gb = Bw + (size_t)(bn * 256 + rws) * K + ((tid & 3) ^ (rws & 3)) * 8;
  f32x4 acc[4][8] = {};

  auto STAGE = [&](int t, int buf) {
#pragma unroll
    for (int c2 = 0; c2 < 2; ++c2)
      GLD_LDS(ga + (size_t)c2 * 64 * K + t * 32, (char*)&As[buf][0] + c2 * 4096 + wv_ * 1024);
#pragma unroll
    for (int c2 = 0; c2 < 4; ++c2)
      GLD_LDS(gb + (size_t)c2 * 64 * K + t * 32, (char*)&Bs[buf][0] + c2 * 4096 + wv_ * 1024);
  };
  auto COMPUTE = [&](int buf) {
    bf16x8 af[4], bfv[8];
#pragma unroll
    for (int i = 0; i < 4; ++i) {
      int arow = wm + i * 16 + l15;
      af[i] = *reinterpret_cast<const bf16x8*>(
          (const char*)&As[buf][0] + arow * 64 + ((lhi ^ (arow & 3)) * 16));
    }
#pragma unroll
    for (int j = 0; j < 8; ++j) {
      int br = wn + j * 16 + l15;
      bfv[j] = *reinterpret_cast<const bf16x8*>(
          (const char*)&Bs[buf][0] + br * 64 + ((lhi ^ (br & 3)) * 16));
    }
#pragma unroll
    for (int i = 0; i < 4; ++i)
#pragma unroll
      for (int j = 0; j < 8; ++j)
        acc[i][j] = __builtin_amdgcn_mfma_f32_16x16x32_bf16(af[i], bfv[j], acc[i][j], 0, 0, 0);
  };

  STAGE(0, 0);
  STAGE(1, 1);
#pragma unroll 1
  for (int tt = 0; tt < 30; tt += 3) {
    VMCNT(6); BARRIER(); COMPUTE(0); STAGE(tt + 2, 2);
    VMCNT(6); BARRIER(); COMPUTE(1); STAGE(tt + 3, 0);
    VMCNT(6); BARRIER(); COMPUTE(2); STAGE(tt + 4, 1);
  }
  VMCNT(6); BARRIER(); COMPUTE(0);
  VMCNT(0); BARRIER(); COMPUTE(1);

#pragma unroll
  for (int i = 0; i < 4; ++i)
#pragma unroll
    for (int j = 0; j < 8; ++j) {
      int n = bn * 256 + wn + j * 16 + l15;
      float bv2 = bias[n];
#pragma unroll
      for (int r = 0; r < 4; ++r) {
        int m = bm * 128 + wm + i * 16 + lhi * 4 + r;
        Cout[(size_t)m * 1024 + n] = acc[i][j][r] + bv2;
      }
    }
}

// ---------------- flash attention: barrier-free, per-wave private K/V LDS ----------------
static __device__ __forceinline__ void qk2(const bf16_t* Kbuf, const bf16x8 qfA[4],
                                           const bf16x8 qfB[4], int l31, int h,
                                           f32x16& sA, f32x16& sB) {
  sA = {}; sB = {};
  __builtin_amdgcn_s_setprio(1);
#pragma unroll
  for (int c = 0; c < 4; ++c) {
    bf16x8 kf = *reinterpret_cast<const bf16x8*>(Kbuf + l31 * 72 + h * 8 + 16 * c);
    sA = __builtin_amdgcn_mfma_f32_32x32x16_bf16(kf, qfA[c], sA, 0, 0, 0);
    sB = __builtin_amdgcn_mfma_f32_32x32x16_bf16(kf, qfB[c], sB, 0, 0, 0);
  }
  __builtin_amdgcn_s_setprio(0);
}

static __device__ __forceinline__ void softmax_tile(
    const f32x16& sv, uint mb, int h, f32x16& o0, f32x16& o1,
    float& mrun, float& lsum, bf16x8& pa0, bf16x8& pa1) {
  const uint mbh = mb >> (h << 4);
  float a0 = fmaxf(fmaxf(sv[0], sv[1]), sv[2]);
  float a1 = fmaxf(fmaxf(sv[3], sv[4]), sv[5]);
  float a2 = fmaxf(fmaxf(sv[6], sv[7]), sv[8]);
  float a3 = fmaxf(fmaxf(sv[9], sv[10]), sv[11]);
  float a4 = fmaxf(fmaxf(sv[12], sv[13]), sv[14]);
  float b0 = fmaxf(fmaxf(a0, a1), a2);
  float mt = fmaxf(fmaxf(b0, fmaxf(a3, a4)), sv[15]);
  if (!__all(mt - mrun <= 8.0f)) {  // defer-max safety (log2 units); ~never taken
    float mtf = fmaxf(mt, __shfl_xor(mt, 32));
    float mnew = fmaxf(mrun, mtf);
    float alpha = __builtin_amdgcn_exp2f(mrun - mnew);
    lsum *= alpha;
#pragma unroll
    for (int r = 0; r < 16; ++r) {
      float ar = __shfl(alpha, (r & 3) + 8 * (r >> 2) + 4 * h);
      o0[r] *= ar; o1[r] *= ar;
    }
    mrun = mnew;
  }
  float p[16];
#pragma unroll
  for (int r = 0; r < 16; ++r) {
    float pv = __builtin_amdgcn_exp2f(sv[r] - mrun);
    uint smask = (uint)__builtin_amdgcn_sbfe((int)mbh, r, 1);  // 0 or ~0
    p[r] = __builtin_bit_cast(float, __builtin_bit_cast(uint, pv) & smask);
  }
  float t0 = p[0] + p[1], t1 = p[2] + p[3], t2 = p[4] + p[5], t3 = p[6] + p[7];
  float t4 = p[8] + p[9], t5 = p[10] + p[11], t6 = p[12] + p[13], t7 = p[14] + p[15];
  t0 += t1; t2 += t3; t4 += t5; t6 += t7;
  lsum += (t0 + t2) + (t4 + t6);  // per-lane half-row sum; cross-half deferred
  uint dw[8];
#pragma unroll
  for (int i = 0; i < 8; ++i) dw[i] = cvt_pk(p[2 * i], p[2 * i + 1]);
  uint e0 = (uint)__shfl_xor((int)(h ? dw[0] : dw[2]), 32);
  uint e1 = (uint)__shfl_xor((int)(h ? dw[1] : dw[3]), 32);
  uint e2 = (uint)__shfl_xor((int)(h ? dw[4] : dw[6]), 32);
  uint e3 = (uint)__shfl_xor((int)(h ? dw[5] : dw[7]), 32);
  uint4v ua0 = {h ? e0 : dw[0], h ? e1 : dw[1], h ? dw[2] : e0, h ? dw[3] : e1};
  uint4v ua1 = {h ? e2 : dw[4], h ? e3 : dw[5], h ? dw[6] : e2, h ? dw[7] : e3};
  pa0 = __builtin_bit_cast(bf16x8, ua0);
  pa1 = __builtin_bit_cast(bf16x8, ua1);
}

static __device__ __forceinline__ void pv2(const bf16_t* Vbuf,
                                           bf16x8 paA0, bf16x8 paA1, bf16x8 paB0, bf16x8 paB1,
                                           int l31, int h,
                                           f32x16& oA0, f32x16& oA1, f32x16& oB0, f32x16& oB1) {
  bf16x8 v00 = *reinterpret_cast<const bf16x8*>(Vbuf + l31 * 40 + h * 8);
  bf16x8 v01 = *reinterpret_cast<const bf16x8*>(Vbuf + l31 * 40 + 16 + h * 8);
  bf16x8 v10 = *reinterpret_cast<const bf16x8*>(Vbuf + (32 + l31) * 40 + h * 8);
  bf16x8 v11 = *reinterpret_cast<const bf16x8*>(Vbuf + (32 + l31) * 40 + 16 + h * 8);
  __builtin_amdgcn_s_setprio(1);
  oA0 = __builtin_amdgcn_mfma_f32_32x32x16_bf16(paA0, v00, oA0, 0, 0, 0);
  oA0 = __builtin_amdgcn_mfma_f32_32x32x16_bf16(paA1, v01, oA0, 0, 0, 0);
  oA1 = __builtin_amdgcn_mfma_f32_32x32x16_bf16(paA0, v10, oA1, 0, 0, 0);
  oA1 = __builtin_amdgcn_mfma_f32_32x32x16_bf16(paA1, v11, oA1, 0, 0, 0);
  oB0 = __builtin_amdgcn_mfma_f32_32x32x16_bf16(paB0, v00, oB0, 0, 0, 0);
  oB0 = __builtin_amdgcn_mfma_f32_32x32x16_bf16(paB1, v01, oB0, 0, 0, 0);
  oB1 = __builtin_amdgcn_mfma_f32_32x32x16_bf16(paB0, v10, oB1, 0, 0, 0);
  oB1 = __builtin_amdgcn_mfma_f32_32x32x16_bf16(paB1, v11, oB1, 0, 0, 0);
  __builtin_amdgcn_s_setprio(0);
}

// 256-thread blocks, 4 waves x 64 q-rows; each wave owns PRIVATE double-buffered K/V LDS.
// NO __syncthreads anywhere: no cross-wave LDS sharing -> race-free by construction;
// per-wave ordering enforced by compiler vmcnt (global->reg) and lgkmcnt (ds r/w).
__global__ __launch_bounds__(256, 2) void attn_kernel(
    const bf16_t* __restrict__ Qp, const bf16_t* __restrict__ Kp,
    const bf16_t* __restrict__ Vt, const uint* __restrict__ maskbits,
    bf16_t* __restrict__ Xb) {
  constexpr int S = 2048, D = 1024;
  __shared__ __align__(16) bf16_t Ks[4][2][32][72];  // per-wave, padded 9-granule rows
  __shared__ __align__(16) bf16_t Vs[4][2][64][40];  // per-wave, padded 5-granule rows
  const int tid = threadIdx.x;
  const int wv_ = tid >> 6, lane = tid & 63;
  const int l31 = lane & 31, h = lane >> 5;
  const int blk = blockIdx.x;                     // 512 blocks
  const int bh = blk & 63, qt = blk >> 6;         // qt 0..7
  const int b = bh >> 4, hd = bh & 15;
  const int q0 = qt * 256 + wv_ * 64;             // wave owns q0..q0+63

  // per-wave staging decomposition: 4 chunks of 16B each for K and V per lane
  const int kRow = lane >> 3, kSlot = lane & 7;   // K rows kRow+8c, 8 slots/row
  const int vRow = lane >> 2, vSlot = lane & 3;   // V rows vRow+16c, 4 slots/row
  const bf16_t* gK = Kp + ((size_t)b * S + kRow) * D + hd * 64 + kSlot * 8;
  const bf16_t* gV = Vt + ((size_t)b * 1024 + hd * 64 + vRow) * (size_t)S + vSlot * 8;

  // Q fragments: A = cols q0+l31, B = cols q0+32+l31; rows d = 16c + 8h + j
  const bf16_t* qbase = Qp + (size_t)(b * S + q0 + l31) * D + hd * 64 + h * 8;
  bf16x8 qfA[4], qfB[4];
#pragma unroll
  for (int c = 0; c < 4; ++c) {
    qfA[c] = *reinterpret_cast<const bf16x8*>(qbase + 16 * c);
    qfB[c] = *reinterpret_cast<const bf16x8*>(qbase + (size_t)32 * D + 16 * c);
  }

  const uint* mbase = maskbits + q0 + l31;

  f32x16 oA0 = {}, oA1 = {}, oB0 = {}, oB1 = {};
  float mrunA = 0.f, lsumA = 0.f, mrunB = 0.f, lsumB = 0.f;
  bf16x8 paA0, paA1, paB0, paB1;

  auto K_LOAD = [&](int t, bf16x8* R) {
#pragma unroll
    for (int c = 0; c < 4; ++c)
      R[c] = *reinterpret_cast<const bf16x8*>(gK + (size_t)(t * 32 + 8 * c) * D);
  };
  auto V_LOAD = [&](int t, bf16x8* R) {
#pragma unroll
    for (int c = 0; c < 4; ++c)
      R[c] = *reinterpret_cast<const bf16x8*>(gV + (size_t)(16 * c) * S + t * 32);
  };
  auto K_WRITE = [&](const bf16x8* R, int buf) {
#pragma unroll
    for (int c = 0; c < 4; ++c)
      *reinterpret_cast<bf16x8*>(&Ks[wv_][buf][8 * c + kRow][kSlot * 8]) = R[c];
  };
  auto V_WRITE = [&](const bf16x8* R, int buf) {
#pragma unroll
    for (int c = 0; c < 4; ++c)
      *reinterpret_cast<bf16x8*>(&Vs[wv_][buf][16 * c + vRow][vSlot * 8]) = R[c];
  };

  // prologue: stage tile 0 into buf 0
  {
    bf16x8 kr[4], vr[4];
    K_LOAD(0, kr);
    V_LOAD(0, vr);
    K_WRITE(kr, 0);
    V_WRITE(vr, 0);
  }

#pragma unroll 2
  for (int t = 0; t < 64; ++t) {
    const int cur = t & 1, nxt = cur ^ 1;
    const bool pf = (t < 63);
    bf16x8 kr[4], vr[4];
    if (pf) {
      K_LOAD(t + 1, kr);
      V_LOAD(t + 1, vr);
    }
    uint mnA = mbase[(size_t)t * 2048];
    uint mnB = mbase[(size_t)t * 2048 + 32];
    f32x16 sA, sB;
    qk2(&Ks[wv_][cur][0][0], qfA, qfB, l31, h, sA, sB);
    softmax_tile(sA, mnA, h, oA0, oA1, mrunA, lsumA, paA0, paA1);
    softmax_tile(sB, mnB, h, oB0, oB1, mrunB, lsumB, paB0, paB1);
    pv2(&Vs[wv_][cur][0][0], paA0, paA1, paB0, paB1, l31, h, oA0, oA1, oB0, oB1);
    if (pf) {
      K_WRITE(kr, nxt);  // compiler inserts vmcnt for kr/vr, lgkm ordering for reuse
      V_WRITE(vr, nxt);
    }
  }

  // finish row sums (one cross-half exchange each), normalize, store
  lsumA += __shfl_xor(lsumA, 32);
  lsumB += __shfl_xor(lsumB, 32);
  float linvA = __builtin_amdgcn_rcpf(lsumA);
  float linvB = __builtin_amdgcn_rcpf(lsumB);
  bf16_t* xrow = Xb + (size_t)(b * S + q0) * D + hd * 64 + l31;
#pragma unroll
  for (int r = 0; r < 16; ++r) {
    int qrow = (r & 3) + 8 * (r >> 2) + 4 * h;
    float lrA = __shfl(linvA, qrow);
    float lrB = __shfl(linvB, qrow);
    xrow[(size_t)qrow * D] = f2bf(oA0[r] * lrA);
    xrow[(size_t)qrow * D + 32] = f2bf(oA1[r] * lrA);
    xrow[(size_t)(qrow + 32) * D] = f2bf(oB0[r] * lrB);
    xrow[(size_t)(qrow + 32) * D + 32] = f2bf(oB1[r] * lrB);
  }
}

// ---------------- launch ----------------
extern "C" void kernel_launch(void* const* d_in, const int* in_sizes, int n_in,
                              void* d_out, int out_size, void* d_ws, size_t ws_size,
                              hipStream_t stream) {
  const float* q = (const float*)d_in[0];
  const float* k = (const float*)d_in[1];
  const float* v = (const float*)d_in[2];
  const int* mask = (const int*)d_in[3];
  const float* w_q = (const float*)d_in[4];
  const float* b_q = (const float*)d_in[5];
  const float* w_k = (const float*)d_in[6];
  const float* b_k = (const float*)d_in[7];
  const float* w_v = (const float*)d_in[8];
  const float* b_v = (const float*)d_in[9];
  const float* w_o = (const float*)d_in[10];
  const float* b_o = (const float*)d_in[11];

  char* ws = (char*)d_ws;
  const size_t SZ = (size_t)8192 * 1024 * 2;  // 16 MiB
  bf16_t* Qp = (bf16_t*)(ws + 0 * SZ);
  bf16_t* Kp = (bf16_t*)(ws + 1 * SZ);
  bf16_t* Vt = (bf16_t*)(ws + 2 * SZ);
  bf16_t* Xb = (bf16_t*)(ws + 3 * SZ);
  uint* maskB = (uint*)(ws + 4 * SZ);
  bf16_t* wqb = (bf16_t*)(ws + 4 * SZ + 8388608);
  bf16_t* wkb = wqb + 1048576;
  bf16_t* wvb = wkb + 1048576;
  bf16_t* wob = wvb + 1048576;

  cvt4_f2b<<<4096, 256, 0, stream>>>(w_q, w_k, w_v, w_o, wqb, wkb, wvb, wob);
  mask_bits_k<<<512, 256, 0, stream>>>(mask, maskB);

  dim3 g3(64, 4, 3);
  qkv_gemm<<<g3, 256, 0, stream>>>(q, k, v, wqb, wkb, wvb, b_q, b_k, b_v, Qp, Kp, Vt);
  attn_kernel<<<512, 256, 0, stream>>>(Qp, Kp, Vt, maskB, Xb);
  gemm_o<<<dim3(64, 4), 256, 0, stream>>>(Xb, wob, b_o, (float*)d_out);
}